// Round 1
// baseline (878.132 us; speedup 1.0000x reference)
//
#include <hip/hip_runtime.h>
#include <math.h>

// Problem constants
#define NQ   8192   // queries (B)
#define NK   4096   // keys (P)
#define DIM  768
#define LL   8      // e_p middle dim

// GEMM tiling
#define TQ   128    // queries per block
#define TKt  128    // keys per k-tile
#define KT   4      // k-tiles per block -> 512 keys/block
#define NKB  8      // key-block splits (grid.y)
#define DC   32     // d-chunk staged in LDS

// -------------------- Kernel A: inverse key norms --------------------
__global__ __launch_bounds__(256) void ek_inv_norms(const float* __restrict__ ek,
                                                    float* __restrict__ inv_n) {
    const int wave = threadIdx.x >> 6;      // 4 waves/block
    const int lane = threadIdx.x & 63;
    const int row  = blockIdx.x * 4 + wave; // 1024 blocks * 4 = 4096
    if (row >= NK) return;
    const float* r = ek + (size_t)row * DIM;
    float s = 0.f;
#pragma unroll
    for (int j = 0; j < DIM / 64; ++j) {
        float v = r[lane + j * 64];
        s = fmaf(v, v, s);
    }
#pragma unroll
    for (int off = 32; off > 0; off >>= 1) s += __shfl_down(s, off);
    if (lane == 0) inv_n[row] = 1.0f / fmaxf(sqrtf(s), 1e-12f);
}

// -------------------- Kernel B: scores + fused argmax --------------------
// grid (64, 8): block = 128 queries x 512 keys. 256 threads, 8x8 microtile.
__global__ __launch_bounds__(256) void score_argmax(const float* __restrict__ xq,
                                                    const float* __restrict__ ek,
                                                    const float* __restrict__ inv_n,
                                                    float* __restrict__ cand_v,
                                                    int* __restrict__ cand_i) {
    __shared__ float xs[DC][TQ + 4];   // [d][q], transposed for row-contig reads
    __shared__ float es[DC][TKt + 4];  // [d][k]
    __shared__ float rv[16][TQ];
    __shared__ int   ri[16][TQ];

    const int t  = threadIdx.x;
    const int tq = t & 15;        // 16 q-groups
    const int tk = t >> 4;        // 16 k-groups
    const int q0 = tq * 8;
    const int k0 = tk * 8;
    const int qb = blockIdx.x;    // 0..63
    const int kb = blockIdx.y;    // 0..7
    const int qbase = qb * TQ;

    float bestv[8];
    int   besti[8];
#pragma unroll
    for (int i = 0; i < 8; ++i) { bestv[i] = -INFINITY; besti[i] = 0x7fffffff; }

    const int d_stage = t & 31;   // staging: this thread's d column
    const int qo      = t >> 5;   // staging: row offset 0..7

    for (int kt = 0; kt < KT; ++kt) {
        const int kbase = kb * (KT * TKt) + kt * TKt;
        float acc[8][8];
#pragma unroll
        for (int i = 0; i < 8; ++i)
#pragma unroll
            for (int j = 0; j < 8; ++j) acc[i][j] = 0.f;

        for (int dc = 0; dc < DIM / DC; ++dc) {
            __syncthreads();  // previous chunk reads done
#pragma unroll
            for (int g = 0; g < 16; ++g) {
                const int r = qo + g * 8;  // 0..127, each exactly once
                xs[d_stage][r] = xq[(size_t)(qbase + r) * DIM + dc * DC + d_stage];
                es[d_stage][r] = ek[(size_t)(kbase + r) * DIM + dc * DC + d_stage];
            }
            __syncthreads();
#pragma unroll
            for (int d = 0; d < DC; ++d) {
                const float4 xa = *(const float4*)&xs[d][q0];
                const float4 xb = *(const float4*)&xs[d][q0 + 4];
                const float4 ea = *(const float4*)&es[d][k0];
                const float4 eb = *(const float4*)&es[d][k0 + 4];
                const float xv[8] = {xa.x, xa.y, xa.z, xa.w, xb.x, xb.y, xb.z, xb.w};
                const float ev[8] = {ea.x, ea.y, ea.z, ea.w, eb.x, eb.y, eb.z, eb.w};
#pragma unroll
                for (int i = 0; i < 8; ++i)
#pragma unroll
                    for (int j = 0; j < 8; ++j)
                        acc[i][j] = fmaf(xv[i], ev[j], acc[i][j]);
            }
        }
        // fold this k-tile into the per-thread running best
#pragma unroll
        for (int j = 0; j < 8; ++j) {
            const int k   = kbase + k0 + j;
            const float s = inv_n[k];
#pragma unroll
            for (int i = 0; i < 8; ++i) {
                const float v = acc[i][j] * s;
                if (v > bestv[i] || (v == bestv[i] && k < besti[i])) {
                    bestv[i] = v;
                    besti[i] = k;
                }
            }
        }
    }

    // cross-thread reduce: 16 tk-groups hold partials for the same 8 queries
    __syncthreads();
#pragma unroll
    for (int i = 0; i < 8; ++i) {
        rv[tk][q0 + i] = bestv[i];
        ri[tk][q0 + i] = besti[i];
    }
    __syncthreads();
    if (t < TQ) {
        float bv = -INFINITY;
        int   bi = 0x7fffffff;
#pragma unroll
        for (int g = 0; g < 16; ++g) {
            const float v = rv[g][t];
            const int   i = ri[g][t];
            if (v > bv || (v == bv && i < bi)) { bv = v; bi = i; }
        }
        cand_v[(size_t)kb * NQ + qbase + t] = bv;
        cand_i[(size_t)kb * NQ + qbase + t] = bi;
    }
}

// -------------------- Kernel C: merge + gather + passthrough --------------------
// one block per query row b
__global__ __launch_bounds__(256) void gather_merge(const float* __restrict__ cand_v,
                                                    const int* __restrict__ cand_i,
                                                    const float* __restrict__ e_p,
                                                    const float* __restrict__ x_block,
                                                    float* __restrict__ out) {
    const int b = blockIdx.x;
    __shared__ int ksel;
    if (threadIdx.x == 0) {
        float bv = -INFINITY;
        int   bi = 0x7fffffff;
#pragma unroll
        for (int kb = 0; kb < NKB; ++kb) {
            const float v = cand_v[(size_t)kb * NQ + b];
            const int   i = cand_i[(size_t)kb * NQ + b];
            if (v > bv || (v == bv && i < bi)) { bv = v; bi = i; }
        }
        ksel = bi;
    }
    __syncthreads();
    const int k = ksel;

    const float4* src = (const float4*)e_p + (size_t)k * (LL * DIM / 4);  // 1536 float4
    float4* o = (float4*)out;
    const int t = threadIdx.x;
    const size_t EK4 = (size_t)NQ * 4 * (DIM / 4);  // 6,291,456 float4 per half
#pragma unroll
    for (int j = 0; j < 6; ++j) {
        const int f   = j * 256 + t;   // 0..1535
        const int row = f / (DIM / 4); // 0..7
        const int col = f % (DIM / 4);
        const float4 v = src[f];
        if (row < 4)
            o[((size_t)b * 4 + row) * (DIM / 4) + col] = v;
        else
            o[EK4 + ((size_t)b * 4 + (row - 4)) * (DIM / 4) + col] = v;
    }
    if (t < DIM / 4)
        o[2 * EK4 + (size_t)b * (DIM / 4) + t] =
            ((const float4*)x_block)[(size_t)b * (DIM / 4) + t];
}

// -------------------- launch --------------------
extern "C" void kernel_launch(void* const* d_in, const int* in_sizes, int n_in,
                              void* d_out, int out_size, void* d_ws, size_t ws_size,
                              hipStream_t stream) {
    const float* x_querry = (const float*)d_in[0];
    const float* x_block  = (const float*)d_in[1];
    const float* e_k      = (const float*)d_in[2];
    const float* e_p      = (const float*)d_in[3];
    // d_in[4] = l (unused; reference asserts e-layer path)

    float* inv_n  = (float*)d_ws;                 // 4096 f32
    float* cand_v = inv_n + NK;                   // 8*8192 f32
    int*   cand_i = (int*)(cand_v + NKB * NQ);    // 8*8192 i32
    float* out    = (float*)d_out;

    ek_inv_norms<<<NK / 4, 256, 0, stream>>>(e_k, inv_n);
    score_argmax<<<dim3(NQ / TQ, NKB), 256, 0, stream>>>(x_querry, e_k, inv_n,
                                                         cand_v, cand_i);
    gather_merge<<<NQ, 256, 0, stream>>>(cand_v, cand_i, e_p, x_block, out);
}

// Round 2
// 354.990 us; speedup vs baseline: 2.4737x; 2.4737x over previous
//
#include <hip/hip_runtime.h>
#include <math.h>

#define NQ   8192
#define NK   4096
#define DIM  768
#define LL   8

typedef __attribute__((ext_vector_type(8))) short short8v;
typedef __attribute__((ext_vector_type(4))) float f32x4;
typedef unsigned long long u64;
typedef unsigned short ushort_t;

// ---------- helpers ----------
__device__ inline unsigned f2bf_bits(float f) {
    unsigned u = __float_as_uint(f);
    return (u + 0x7FFFu + ((u >> 16) & 1u)) >> 16;   // RNE f32->bf16
}
__device__ inline unsigned ordf(float f) {           // monotonic f32->u32
    unsigned u = __float_as_uint(f);
    return (u & 0x80000000u) ? ~u : (u | 0x80000000u);
}

// ---------- prep: split x into bf16 hi/lo, compute margin ----------
__global__ __launch_bounds__(256) void prep_x(const float* __restrict__ xq,
                                              ushort_t* __restrict__ Xh,
                                              ushort_t* __restrict__ Xl,
                                              float* __restrict__ margin) {
    const int wid = threadIdx.x >> 6, lane = threadIdx.x & 63;
    const int row = blockIdx.x * 4 + wid;
    const float* src = xq + (size_t)row * DIM;
    float s2 = 0.f;
#pragma unroll
    for (int j = 0; j < DIM / 64; ++j) {
        const int c = j * 64 + lane;
        float v = src[c];
        s2 = fmaf(v, v, s2);
        unsigned hb = f2bf_bits(v);
        float hv = __uint_as_float(hb << 16);
        unsigned lb = f2bf_bits(v - hv);
        Xh[(size_t)row * DIM + c] = (ushort_t)hb;
        Xl[(size_t)row * DIM + c] = (ushort_t)lb;
    }
#pragma unroll
    for (int off = 32; off; off >>= 1) s2 += __shfl_xor(s2, off);
    if (lane == 0) margin[row] = 4e-4f * sqrtf(s2) + 4e-3f;  // ~1.45x worst-case bound
}

__global__ __launch_bounds__(256) void prep_e(const float* __restrict__ ek,
                                              ushort_t* __restrict__ Eh,
                                              ushort_t* __restrict__ El,
                                              float* __restrict__ inv_n) {
    const int wid = threadIdx.x >> 6, lane = threadIdx.x & 63;
    const int row = blockIdx.x * 4 + wid;
    const float* src = ek + (size_t)row * DIM;
    float s2 = 0.f;
#pragma unroll
    for (int j = 0; j < DIM / 64; ++j) {
        const int c = j * 64 + lane;
        float v = src[c];
        s2 = fmaf(v, v, s2);
        unsigned hb = f2bf_bits(v);
        float hv = __uint_as_float(hb << 16);
        unsigned lb = f2bf_bits(v - hv);
        Eh[(size_t)row * DIM + c] = (ushort_t)hb;
        El[(size_t)row * DIM + c] = (ushort_t)lb;
    }
#pragma unroll
    for (int off = 32; off; off >>= 1) s2 += __shfl_xor(s2, off);
    if (lane == 0) inv_n[row] = 1.0f / fmaxf(sqrtf(s2), 1e-12f);
}

// ---------- compensated bf16 MFMA GEMM: scores = (xh+xl)(eh+el)^T * inv_n ----------
// grid (64,32), 128x128 tile, BK=32, 4 waves of 64x64
__global__ __launch_bounds__(256) void gemm3(const ushort_t* __restrict__ Xh,
                                             const ushort_t* __restrict__ Xl,
                                             const ushort_t* __restrict__ Eh,
                                             const ushort_t* __restrict__ El,
                                             const float* __restrict__ inv_n,
                                             float* __restrict__ scores) {
    __shared__ ushort_t Ah[128 * 40], Al[128 * 40], Bh[128 * 40], Bl[128 * 40];
    const int t = threadIdx.x, lane = t & 63, wid = t >> 6;
    const int wm = wid & 1, wn = wid >> 1;

    // XCD-aware swizzle: contiguous tile chunk per XCD (2048 % 8 == 0 -> bijective)
    const int lin = blockIdx.y * 64 + blockIdx.x;
    const int wg = (lin & 7) * 256 + (lin >> 3);
    const int qb = wg & 63, kb = wg >> 6;
    const int qbase = qb * 128, kbase = kb * 128;

    f32x4 acc[4][4];
#pragma unroll
    for (int mi = 0; mi < 4; ++mi)
#pragma unroll
        for (int ni = 0; ni < 4; ++ni) acc[mi][ni] = (f32x4){0.f, 0.f, 0.f, 0.f};

    const int rr = t >> 2, cc = t & 3;  // staging: 64 rows x 4 chunks per pass

    for (int kk = 0; kk < DIM; kk += 32) {
        __syncthreads();
#pragma unroll
        for (int p = 0; p < 2; ++p) {
            const int row = rr + p * 64;
            const size_t gx = (size_t)(qbase + row) * DIM + kk + cc * 8;
            const size_t ge = (size_t)(kbase + row) * DIM + kk + cc * 8;
            *(short8v*)&Ah[row * 40 + cc * 8] = *(const short8v*)&Xh[gx];
            *(short8v*)&Al[row * 40 + cc * 8] = *(const short8v*)&Xl[gx];
            *(short8v*)&Bh[row * 40 + cc * 8] = *(const short8v*)&Eh[ge];
            *(short8v*)&Bl[row * 40 + cc * 8] = *(const short8v*)&El[ge];
        }
        __syncthreads();

        const int ko = (lane >> 4) * 8;
        short8v ah[4], al[4], bh[4], bl[4];
#pragma unroll
        for (int mi = 0; mi < 4; ++mi) {
            const int r0 = wm * 64 + mi * 16 + (lane & 15);
            ah[mi] = *(const short8v*)&Ah[r0 * 40 + ko];
            al[mi] = *(const short8v*)&Al[r0 * 40 + ko];
        }
#pragma unroll
        for (int ni = 0; ni < 4; ++ni) {
            const int r0 = wn * 64 + ni * 16 + (lane & 15);
            bh[ni] = *(const short8v*)&Bh[r0 * 40 + ko];
            bl[ni] = *(const short8v*)&Bl[r0 * 40 + ko];
        }
#pragma unroll
        for (int mi = 0; mi < 4; ++mi)
#pragma unroll
            for (int ni = 0; ni < 4; ++ni)
                acc[mi][ni] = __builtin_amdgcn_mfma_f32_16x16x32_bf16(ah[mi], bh[ni], acc[mi][ni], 0, 0, 0);
#pragma unroll
        for (int mi = 0; mi < 4; ++mi)
#pragma unroll
            for (int ni = 0; ni < 4; ++ni)
                acc[mi][ni] = __builtin_amdgcn_mfma_f32_16x16x32_bf16(ah[mi], bl[ni], acc[mi][ni], 0, 0, 0);
#pragma unroll
        for (int mi = 0; mi < 4; ++mi)
#pragma unroll
            for (int ni = 0; ni < 4; ++ni)
                acc[mi][ni] = __builtin_amdgcn_mfma_f32_16x16x32_bf16(al[mi], bh[ni], acc[mi][ni], 0, 0, 0);
    }

    // epilogue: C/D layout col=lane&15, row=(lane>>4)*4+reg
    const int rg = lane >> 4, cid = lane & 15;
    float invv[4];
    int key[4];
#pragma unroll
    for (int ni = 0; ni < 4; ++ni) {
        key[ni] = kbase + wn * 64 + ni * 16 + cid;
        invv[ni] = inv_n[key[ni]];
    }
#pragma unroll
    for (int mi = 0; mi < 4; ++mi)
#pragma unroll
        for (int rj = 0; rj < 4; ++rj) {
            const int row = qbase + wm * 64 + mi * 16 + rg * 4 + rj;
#pragma unroll
            for (int ni = 0; ni < 4; ++ni)
                scores[(size_t)row * NK + key[ni]] = acc[mi][ni][rj] * invv[ni];
        }
}

// ---------- scan: per-row max, margin test, exact f32 rescore, argmax ----------
__global__ __launch_bounds__(256) void scan_rescore(const float* __restrict__ scores,
                                                    const float* __restrict__ margin,
                                                    const float* __restrict__ inv_n,
                                                    const float* __restrict__ xq,
                                                    const float* __restrict__ ek,
                                                    int* __restrict__ bestk) {
    const int r = blockIdx.x, t = threadIdx.x, lane = t & 63, wid = t >> 6;
    __shared__ float wmaxs[4];
    __shared__ u64 wbest[4];
    const float* srow = scores + (size_t)r * NK;
    float sc[16];
    float m = -INFINITY;
#pragma unroll
    for (int j = 0; j < 16; ++j) {
        sc[j] = srow[t + j * 256];
        m = fmaxf(m, sc[j]);
    }
#pragma unroll
    for (int off = 32; off; off >>= 1) m = fmaxf(m, __shfl_xor(m, off));
    if (lane == 0) wmaxs[wid] = m;
    __syncthreads();
    m = fmaxf(fmaxf(wmaxs[0], wmaxs[1]), fmaxf(wmaxs[2], wmaxs[3]));
    const float thr = m - margin[r];

    u64 bp = 0;
    const float4* xr = (const float4*)(xq + (size_t)r * DIM);
    for (int j = 0; j < 16; ++j) {
        if (sc[j] >= thr) {
            const int k = t + j * 256;
            const float4* er = (const float4*)(ek + (size_t)k * DIM);
            float s0 = 0.f, s1 = 0.f, s2 = 0.f, s3 = 0.f;
#pragma unroll 8
            for (int p = 0; p < DIM / 4; ++p) {
                const float4 a = xr[p], b = er[p];
                s0 = fmaf(a.x, b.x, s0);
                s1 = fmaf(a.y, b.y, s1);
                s2 = fmaf(a.z, b.z, s2);
                s3 = fmaf(a.w, b.w, s3);
            }
            const float v = ((s0 + s1) + (s2 + s3)) * inv_n[k];
            const u64 p64 = ((u64)ordf(v) << 32) | (unsigned)(NK - 1 - k);
            bp = bp > p64 ? bp : p64;
        }
    }
#pragma unroll
    for (int off = 32; off; off >>= 1) {
        const u64 o = __shfl_xor(bp, off);
        bp = bp > o ? bp : o;
    }
    if (lane == 0) wbest[wid] = bp;
    __syncthreads();
    if (t == 0) {
        u64 b0 = wbest[0];
        b0 = b0 > wbest[1] ? b0 : wbest[1];
        b0 = b0 > wbest[2] ? b0 : wbest[2];
        b0 = b0 > wbest[3] ? b0 : wbest[3];
        bestk[r] = NK - 1 - (int)(unsigned)(b0 & 0xffffffffu);
    }
}

// ---------- gather + passthrough ----------
__global__ __launch_bounds__(256) void gather_out(const int* __restrict__ bestk,
                                                  const float* __restrict__ e_p,
                                                  const float* __restrict__ x_block,
                                                  float* __restrict__ out) {
    const int b = blockIdx.x;
    const int k = bestk[b];
    const float4* src = (const float4*)e_p + (size_t)k * (LL * DIM / 4);
    float4* o = (float4*)out;
    const int t = threadIdx.x;
    const size_t EK4 = (size_t)NQ * 4 * (DIM / 4);
#pragma unroll
    for (int j = 0; j < 6; ++j) {
        const int f = j * 256 + t;
        const int row = f / (DIM / 4);
        const int col = f % (DIM / 4);
        const float4 v = src[f];
        if (row < 4)
            o[((size_t)b * 4 + row) * (DIM / 4) + col] = v;
        else
            o[EK4 + ((size_t)b * 4 + (row - 4)) * (DIM / 4) + col] = v;
    }
    if (t < DIM / 4)
        o[2 * EK4 + (size_t)b * (DIM / 4) + t] =
            ((const float4*)x_block)[(size_t)b * (DIM / 4) + t];
}

// ---------- launch ----------
extern "C" void kernel_launch(void* const* d_in, const int* in_sizes, int n_in,
                              void* d_out, int out_size, void* d_ws, size_t ws_size,
                              hipStream_t stream) {
    const float* x_querry = (const float*)d_in[0];
    const float* x_block  = (const float*)d_in[1];
    const float* e_k      = (const float*)d_in[2];
    const float* e_p      = (const float*)d_in[3];

    // scratch carved from d_out (226.5 MB); all consumed before gather overwrites it
    char* base = (char*)d_out;
    ushort_t* Xh   = (ushort_t*)(base);                 // 12,582,912 B
    ushort_t* Xl   = (ushort_t*)(base + 12582912);      // 12,582,912 B
    ushort_t* Eh   = (ushort_t*)(base + 25165824);      //  6,291,456 B
    ushort_t* El   = (ushort_t*)(base + 31457280);      //  6,291,456 B
    float*    invn = (float*)(base + 37748736);         //     16,384 B
    float*    marg = (float*)(base + 37765120);         //     32,768 B
    float*    scor = (float*)(base + 37797888);         // 134,217,728 B -> ends 172,015,616
    int*      bestk = (int*)d_ws;                       // 32 KB in ws

    prep_x<<<NQ / 4, 256, 0, stream>>>(x_querry, Xh, Xl, marg);
    prep_e<<<NK / 4, 256, 0, stream>>>(e_k, Eh, El, invn);
    gemm3<<<dim3(64, 32), 256, 0, stream>>>(Xh, Xl, Eh, El, invn, scor);
    scan_rescore<<<NQ, 256, 0, stream>>>(scor, marg, invn, x_querry, e_k, bestk);
    gather_out<<<NQ, 256, 0, stream>>>(bestk, e_p, x_block, (float*)d_out);
}

// Round 3
// 251.812 us; speedup vs baseline: 3.4872x; 1.4097x over previous
//
#include <hip/hip_runtime.h>
#include <math.h>

#define NQ   8192
#define NK   4096
#define DIM  768
#define LL   8

typedef _Float16 f16;
typedef __attribute__((ext_vector_type(8))) _Float16 f16x8;
typedef __attribute__((ext_vector_type(4))) float f32x4;
typedef unsigned long long u64;

__device__ inline unsigned ordf(float f) {           // monotonic f32->u32
    unsigned u = __float_as_uint(f);
    return (u & 0x80000000u) ? ~u : (u | 0x80000000u);
}

// ---------- prep: f16 conversion of x (rows 0..8191) and e_k (rows 8192..12287) ----------
__global__ __launch_bounds__(256) void prep(const float* __restrict__ xq,
                                            const float* __restrict__ ek,
                                            f16* __restrict__ Xh,
                                            f16* __restrict__ Eh,
                                            float* __restrict__ margin,
                                            float* __restrict__ inv_n) {
    const int wid = threadIdx.x >> 6, lane = threadIdx.x & 63;
    const int row = blockIdx.x * 4 + wid;              // 0..12287
    const bool isX = row < NQ;
    const float* src = isX ? xq + (size_t)row * DIM : ek + (size_t)(row - NQ) * DIM;
    f16* dst = isX ? Xh + (size_t)row * DIM : Eh + (size_t)(row - NQ) * DIM;
    float s2 = 0.f;
#pragma unroll
    for (int j = 0; j < DIM / 64; ++j) {
        const int c = j * 64 + lane;
        const float v = src[c];
        s2 = fmaf(v, v, s2);
        dst[c] = (f16)v;                               // RNE
    }
#pragma unroll
    for (int off = 32; off; off >>= 1) s2 += __shfl_xor(s2, off);
    if (lane == 0) {
        if (isX) margin[row] = sqrtf(s2) * 1.5e-4f + 2e-3f;   // ~13 sigma of fp16 noise
        else     inv_n[row - NQ] = 1.0f / fmaxf(sqrtf(s2), 1e-12f);
    }
}

// ---------- single-pass fp16 MFMA GEMM: scor_f16[b][k] = (xh.eh) * inv_n[k] ----------
// grid (64,32), 128x128 tile, BK=32, 4 waves of 64x64  (structure verified in round 2)
__global__ __launch_bounds__(256) void gemm1(const f16* __restrict__ Xh,
                                             const f16* __restrict__ Eh,
                                             const float* __restrict__ inv_n,
                                             f16* __restrict__ scor) {
    __shared__ f16 Ah[128 * 40], Bh[128 * 40];
    const int t = threadIdx.x, lane = t & 63, wid = t >> 6;
    const int wm = wid & 1, wn = wid >> 1;

    // XCD-aware bijective swizzle (2048 % 8 == 0)
    const int lin = blockIdx.y * 64 + blockIdx.x;
    const int wg = (lin & 7) * 256 + (lin >> 3);
    const int qb = wg & 63, kb = wg >> 6;
    const int qbase = qb * 128, kbase = kb * 128;

    f32x4 acc[4][4];
#pragma unroll
    for (int mi = 0; mi < 4; ++mi)
#pragma unroll
        for (int ni = 0; ni < 4; ++ni) acc[mi][ni] = (f32x4){0.f, 0.f, 0.f, 0.f};

    const int rr = t >> 2, cc = t & 3;

    for (int kk = 0; kk < DIM; kk += 32) {
        __syncthreads();
#pragma unroll
        for (int p = 0; p < 2; ++p) {
            const int row = rr + p * 64;
            *(f16x8*)&Ah[row * 40 + cc * 8] =
                *(const f16x8*)&Xh[(size_t)(qbase + row) * DIM + kk + cc * 8];
            *(f16x8*)&Bh[row * 40 + cc * 8] =
                *(const f16x8*)&Eh[(size_t)(kbase + row) * DIM + kk + cc * 8];
        }
        __syncthreads();

        const int ko = (lane >> 4) * 8;
        f16x8 ah[4], bh[4];
#pragma unroll
        for (int mi = 0; mi < 4; ++mi)
            ah[mi] = *(const f16x8*)&Ah[(wm * 64 + mi * 16 + (lane & 15)) * 40 + ko];
#pragma unroll
        for (int ni = 0; ni < 4; ++ni)
            bh[ni] = *(const f16x8*)&Bh[(wn * 64 + ni * 16 + (lane & 15)) * 40 + ko];
#pragma unroll
        for (int mi = 0; mi < 4; ++mi)
#pragma unroll
            for (int ni = 0; ni < 4; ++ni)
                acc[mi][ni] = __builtin_amdgcn_mfma_f32_16x16x32_f16(ah[mi], bh[ni], acc[mi][ni], 0, 0, 0);
    }

    // epilogue (layout verified round 2): col=lane&15, row=(lane>>4)*4+reg
    const int rg = lane >> 4, cid = lane & 15;
    float invv[4];
    int key[4];
#pragma unroll
    for (int ni = 0; ni < 4; ++ni) {
        key[ni] = kbase + wn * 64 + ni * 16 + cid;
        invv[ni] = inv_n[key[ni]];
    }
#pragma unroll
    for (int mi = 0; mi < 4; ++mi)
#pragma unroll
        for (int rj = 0; rj < 4; ++rj) {
            const int row = qbase + wm * 64 + mi * 16 + rg * 4 + rj;
#pragma unroll
            for (int ni = 0; ni < 4; ++ni)
                scor[(size_t)row * NK + key[ni]] = (f16)(acc[mi][ni][rj] * invv[ni]);
        }
}

// ---------- scan: row max over f16 scores, margin test, exact f32 rescore, argmax ----------
__global__ __launch_bounds__(256) void scan_rescore(const f16* __restrict__ scor,
                                                    const float* __restrict__ margin,
                                                    const float* __restrict__ inv_n,
                                                    const float* __restrict__ xq,
                                                    const float* __restrict__ ek,
                                                    int* __restrict__ bestk) {
    const int r = blockIdx.x, t = threadIdx.x, lane = t & 63, wid = t >> 6;
    __shared__ float wmaxs[4];
    __shared__ u64 wbest[4];
    const f16* srow = scor + (size_t)r * NK + t * 16;
    const f16x8 s0 = *(const f16x8*)srow;
    const f16x8 s1 = *(const f16x8*)(srow + 8);
    float sc[16];
    float m = -INFINITY;
#pragma unroll
    for (int j = 0; j < 8; ++j) { sc[j] = (float)s0[j]; sc[j + 8] = (float)s1[j]; }
#pragma unroll
    for (int j = 0; j < 16; ++j) m = fmaxf(m, sc[j]);
#pragma unroll
    for (int off = 32; off; off >>= 1) m = fmaxf(m, __shfl_xor(m, off));
    if (lane == 0) wmaxs[wid] = m;
    __syncthreads();
    m = fmaxf(fmaxf(wmaxs[0], wmaxs[1]), fmaxf(wmaxs[2], wmaxs[3]));
    const float thr = m - margin[r];

    u64 bp = 0;
    const float4* xr = (const float4*)(xq + (size_t)r * DIM);
#pragma unroll 1
    for (int j = 0; j < 16; ++j) {
        if (sc[j] >= thr) {
            const int k = t * 16 + j;
            const float4* er = (const float4*)(ek + (size_t)k * DIM);
            float a0 = 0.f, a1 = 0.f, a2 = 0.f, a3 = 0.f;
#pragma unroll 8
            for (int p = 0; p < DIM / 4; ++p) {
                const float4 a = xr[p], b = er[p];
                a0 = fmaf(a.x, b.x, a0);
                a1 = fmaf(a.y, b.y, a1);
                a2 = fmaf(a.z, b.z, a2);
                a3 = fmaf(a.w, b.w, a3);
            }
            const float v = ((a0 + a1) + (a2 + a3)) * inv_n[k];
            const u64 p64 = ((u64)ordf(v) << 32) | (unsigned)(NK - 1 - k);
            bp = bp > p64 ? bp : p64;
        }
    }
#pragma unroll
    for (int off = 32; off; off >>= 1) {
        const u64 o = __shfl_xor(bp, off);
        bp = bp > o ? bp : o;
    }
    if (lane == 0) wbest[wid] = bp;
    __syncthreads();
    if (t == 0) {
        u64 b0 = wbest[0];
        b0 = b0 > wbest[1] ? b0 : wbest[1];
        b0 = b0 > wbest[2] ? b0 : wbest[2];
        b0 = b0 > wbest[3] ? b0 : wbest[3];
        bestk[r] = NK - 1 - (int)(unsigned)(b0 & 0xffffffffu);
    }
}

// ---------- gather + passthrough ----------
__global__ __launch_bounds__(256) void gather_out(const int* __restrict__ bestk,
                                                  const float* __restrict__ e_p,
                                                  const float* __restrict__ x_block,
                                                  float* __restrict__ out) {
    const int b = blockIdx.x;
    const int k = bestk[b];
    const float4* src = (const float4*)e_p + (size_t)k * (LL * DIM / 4);
    float4* o = (float4*)out;
    const int t = threadIdx.x;
    const size_t EK4 = (size_t)NQ * 4 * (DIM / 4);
#pragma unroll
    for (int j = 0; j < 6; ++j) {
        const int f = j * 256 + t;
        const int row = f / (DIM / 4);
        const int col = f % (DIM / 4);
        const float4 v = src[f];
        if (row < 4)
            o[((size_t)b * 4 + row) * (DIM / 4) + col] = v;
        else
            o[EK4 + ((size_t)b * 4 + (row - 4)) * (DIM / 4) + col] = v;
    }
    if (t < DIM / 4)
        o[2 * EK4 + (size_t)b * (DIM / 4) + t] =
            ((const float4*)x_block)[(size_t)b * (DIM / 4) + t];
}

// ---------- launch ----------
extern "C" void kernel_launch(void* const* d_in, const int* in_sizes, int n_in,
                              void* d_out, int out_size, void* d_ws, size_t ws_size,
                              hipStream_t stream) {
    const float* x_querry = (const float*)d_in[0];
    const float* x_block  = (const float*)d_in[1];
    const float* e_k      = (const float*)d_in[2];
    const float* e_p      = (const float*)d_in[3];

    // scratch carved from d_out (226.5 MB), fully consumed before gather overwrites it
    char* base = (char*)d_out;
    f16*   Xh   = (f16*)(base);                   // 12,582,912 B
    f16*   Eh   = (f16*)(base + 12582912);        //  6,291,456 B
    float* invn = (float*)(base + 18874368);      //     16,384 B
    float* marg = (float*)(base + 18890752);      //     32,768 B
    f16*   scor = (f16*)(base + 18923520);        // 67,108,864 B -> ends 86,032,384
    int*   bestk = (int*)d_ws;                    // 32 KB

    prep<<<(NQ + NK) / 4, 256, 0, stream>>>(x_querry, e_k, Xh, Eh, marg, invn);
    gemm1<<<dim3(64, 32), 256, 0, stream>>>(Xh, Eh, invn, scor);
    scan_rescore<<<NQ, 256, 0, stream>>>(scor, marg, invn, x_querry, e_k, bestk);
    gather_out<<<NQ, 256, 0, stream>>>(bestk, e_p, x_block, (float*)d_out);
}

// Round 4
// 239.130 us; speedup vs baseline: 3.6722x; 1.0530x over previous
//
#include <hip/hip_runtime.h>
#include <math.h>

#define NQ   8192
#define NK   4096
#define DIM  768
#define LL   8

typedef _Float16 f16;
typedef __attribute__((ext_vector_type(8))) _Float16 f16x8;
typedef __attribute__((ext_vector_type(4))) float f32x4;
typedef unsigned long long u64;

__device__ inline unsigned ordf(float f) {           // monotonic f32->u32
    unsigned u = __float_as_uint(f);
    return (u & 0x80000000u) ? ~u : (u | 0x80000000u);
}

__device__ __forceinline__ void gload16(const void* g, void* l) {
    __builtin_amdgcn_global_load_lds((const __attribute__((address_space(1))) void*)g,
                                     (__attribute__((address_space(3))) void*)l, 16, 0, 0);
}

// ---------- prep: f16 conversion of x (rows 0..8191) and e_k (rows 8192..12287) ----------
__global__ __launch_bounds__(256) void prep(const float* __restrict__ xq,
                                            const float* __restrict__ ek,
                                            f16* __restrict__ Xh,
                                            f16* __restrict__ Eh,
                                            float* __restrict__ margin,
                                            float* __restrict__ inv_n) {
    const int wid = threadIdx.x >> 6, lane = threadIdx.x & 63;
    const int row = blockIdx.x * 4 + wid;              // 0..12287
    const bool isX = row < NQ;
    const float* src = isX ? xq + (size_t)row * DIM : ek + (size_t)(row - NQ) * DIM;
    f16* dst = isX ? Xh + (size_t)row * DIM : Eh + (size_t)(row - NQ) * DIM;
    float s2 = 0.f;
#pragma unroll
    for (int j = 0; j < DIM / 64; ++j) {
        const int c = j * 64 + lane;
        const float v = src[c];
        s2 = fmaf(v, v, s2);
        dst[c] = (f16)v;                               // RNE
    }
#pragma unroll
    for (int off = 32; off; off >>= 1) s2 += __shfl_xor(s2, off);
    if (lane == 0) {
        if (isX) margin[row] = sqrtf(s2) * 1.5e-4f + 2e-3f;   // ~13 sigma of fp16 noise
        else     inv_n[row - NQ] = 1.0f / fmaxf(sqrtf(s2), 1e-12f);
    }
}

// ---------- m97-structure fp16 MFMA GEMM: scor[b][k] = (xh.eh) * inv_n[k] ----------
// 128x128 tile, BK=64, 4 waves (2x2 of 64x64), global_load_lds w=16, linear LDS
__global__ __launch_bounds__(256) void gemm97(const f16* __restrict__ Xh,
                                              const f16* __restrict__ Eh,
                                              const float* __restrict__ inv_n,
                                              f16* __restrict__ scor) {
    __shared__ f16 A[128 * 64], B[128 * 64];
    const int t = threadIdx.x, lane = t & 63, wid = t >> 6;
    const int wm = wid & 1, wn = wid >> 1;
    const int qbase = blockIdx.x * 128, kbase = blockIdx.y * 128;

    f32x4 acc[4][4];
#pragma unroll
    for (int mi = 0; mi < 4; ++mi)
#pragma unroll
        for (int ni = 0; ni < 4; ++ni) acc[mi][ni] = (f32x4){0.f, 0.f, 0.f, 0.f};

    // staging: pass p (0..3): LDS bytes [p*4096 + wid*1024 + lane*16]
    //   -> tile row p*32 + wid*8 + lane/8, col (lane%8)*8 (8 f16 = 16 B)
    const int srow = wid * 8 + (lane >> 3);
    const int scol = (lane & 7) * 8;
    const f16* gA = Xh + (size_t)(qbase + srow) * DIM + scol;
    const f16* gB = Eh + (size_t)(kbase + srow) * DIM + scol;
    f16* lA = &A[wid * 512 + lane * 8];
    f16* lB = &B[wid * 512 + lane * 8];

    for (int kk = 0; kk < DIM; kk += 64) {
        __syncthreads();   // previous iteration's reads done
#pragma unroll
        for (int p = 0; p < 4; ++p) {
            gload16(gA + (size_t)(p * 32) * DIM + kk, lA + p * 2048);
            gload16(gB + (size_t)(p * 32) * DIM + kk, lB + p * 2048);
        }
        __syncthreads();   // compiler drains vmcnt before s_barrier

#pragma unroll
        for (int kk2 = 0; kk2 < 2; ++kk2) {
            const int ko = kk2 * 32 + (lane >> 4) * 8;
            f16x8 ah[4], bh[4];
#pragma unroll
            for (int mi = 0; mi < 4; ++mi)
                ah[mi] = *(const f16x8*)&A[(wm * 64 + mi * 16 + (lane & 15)) * 64 + ko];
#pragma unroll
            for (int ni = 0; ni < 4; ++ni)
                bh[ni] = *(const f16x8*)&B[(wn * 64 + ni * 16 + (lane & 15)) * 64 + ko];
#pragma unroll
            for (int mi = 0; mi < 4; ++mi)
#pragma unroll
                for (int ni = 0; ni < 4; ++ni)
                    acc[mi][ni] = __builtin_amdgcn_mfma_f32_16x16x32_f16(ah[mi], bh[ni], acc[mi][ni], 0, 0, 0);
        }
    }

    // epilogue (layout verified rounds 2-3): col=lane&15, row=(lane>>4)*4+reg
    const int rg = lane >> 4, cid = lane & 15;
    float invv[4];
    int key[4];
#pragma unroll
    for (int ni = 0; ni < 4; ++ni) {
        key[ni] = kbase + wn * 64 + ni * 16 + cid;
        invv[ni] = inv_n[key[ni]];
    }
#pragma unroll
    for (int mi = 0; mi < 4; ++mi)
#pragma unroll
        for (int rj = 0; rj < 4; ++rj) {
            const int row = qbase + wm * 64 + mi * 16 + rg * 4 + rj;
#pragma unroll
            for (int ni = 0; ni < 4; ++ni)
                scor[(size_t)row * NK + key[ni]] = (f16)(acc[mi][ni][rj] * invv[ni]);
        }
}

// ---------- scan: row max over f16 scores, margin test, exact f32 rescore, argmax ----------
__global__ __launch_bounds__(256) void scan_rescore(const f16* __restrict__ scor,
                                                    const float* __restrict__ margin,
                                                    const float* __restrict__ inv_n,
                                                    const float* __restrict__ xq,
                                                    const float* __restrict__ ek,
                                                    int* __restrict__ bestk) {
    const int r = blockIdx.x, t = threadIdx.x, lane = t & 63, wid = t >> 6;
    __shared__ float wmaxs[4];
    __shared__ u64 wbest[4];
    const f16* srow = scor + (size_t)r * NK + t * 16;
    const f16x8 s0 = *(const f16x8*)srow;
    const f16x8 s1 = *(const f16x8*)(srow + 8);
    float sc[16];
    float m = -INFINITY;
#pragma unroll
    for (int j = 0; j < 8; ++j) { sc[j] = (float)s0[j]; sc[j + 8] = (float)s1[j]; }
#pragma unroll
    for (int j = 0; j < 16; ++j) m = fmaxf(m, sc[j]);
#pragma unroll
    for (int off = 32; off; off >>= 1) m = fmaxf(m, __shfl_xor(m, off));
    if (lane == 0) wmaxs[wid] = m;
    __syncthreads();
    m = fmaxf(fmaxf(wmaxs[0], wmaxs[1]), fmaxf(wmaxs[2], wmaxs[3]));
    const float thr = m - margin[r];

    u64 bp = 0;
    const float4* xr = (const float4*)(xq + (size_t)r * DIM);
#pragma unroll 1
    for (int j = 0; j < 16; ++j) {
        if (sc[j] >= thr) {
            const int k = t * 16 + j;
            const float4* er = (const float4*)(ek + (size_t)k * DIM);
            float a0 = 0.f, a1 = 0.f, a2 = 0.f, a3 = 0.f;
#pragma unroll 8
            for (int p = 0; p < DIM / 4; ++p) {
                const float4 a = xr[p], b = er[p];
                a0 = fmaf(a.x, b.x, a0);
                a1 = fmaf(a.y, b.y, a1);
                a2 = fmaf(a.z, b.z, a2);
                a3 = fmaf(a.w, b.w, a3);
            }
            const float v = ((a0 + a1) + (a2 + a3)) * inv_n[k];
            const u64 p64 = ((u64)ordf(v) << 32) | (unsigned)(NK - 1 - k);
            bp = bp > p64 ? bp : p64;
        }
    }
#pragma unroll
    for (int off = 32; off; off >>= 1) {
        const u64 o = __shfl_xor(bp, off);
        bp = bp > o ? bp : o;
    }
    if (lane == 0) wbest[wid] = bp;
    __syncthreads();
    if (t == 0) {
        u64 b0 = wbest[0];
        b0 = b0 > wbest[1] ? b0 : wbest[1];
        b0 = b0 > wbest[2] ? b0 : wbest[2];
        b0 = b0 > wbest[3] ? b0 : wbest[3];
        bestk[r] = NK - 1 - (int)(unsigned)(b0 & 0xffffffffu);
    }
}

// ---------- gather + passthrough ----------
__global__ __launch_bounds__(256) void gather_out(const int* __restrict__ bestk,
                                                  const float* __restrict__ e_p,
                                                  const float* __restrict__ x_block,
                                                  float* __restrict__ out) {
    const int b = blockIdx.x;
    const int k = bestk[b];
    const float4* src = (const float4*)e_p + (size_t)k * (LL * DIM / 4);
    float4* o = (float4*)out;
    const int t = threadIdx.x;
    const size_t EK4 = (size_t)NQ * 4 * (DIM / 4);
#pragma unroll
    for (int j = 0; j < 6; ++j) {
        const int f = j * 256 + t;
        const int row = f / (DIM / 4);
        const int col = f % (DIM / 4);
        const float4 v = src[f];
        if (row < 4)
            o[((size_t)b * 4 + row) * (DIM / 4) + col] = v;
        else
            o[EK4 + ((size_t)b * 4 + (row - 4)) * (DIM / 4) + col] = v;
    }
    if (t < DIM / 4)
        o[2 * EK4 + (size_t)b * (DIM / 4) + t] =
            ((const float4*)x_block)[(size_t)b * (DIM / 4) + t];
}

// ---------- launch ----------
extern "C" void kernel_launch(void* const* d_in, const int* in_sizes, int n_in,
                              void* d_out, int out_size, void* d_ws, size_t ws_size,
                              hipStream_t stream) {
    const float* x_querry = (const float*)d_in[0];
    const float* x_block  = (const float*)d_in[1];
    const float* e_k      = (const float*)d_in[2];
    const float* e_p      = (const float*)d_in[3];

    // scratch carved from d_out (226.5 MB), fully consumed before gather overwrites it
    char* base = (char*)d_out;
    f16*   Xh   = (f16*)(base);                   // 12,582,912 B
    f16*   Eh   = (f16*)(base + 12582912);        //  6,291,456 B
    float* invn = (float*)(base + 18874368);      //     16,384 B
    float* marg = (float*)(base + 18890752);      //     32,768 B
    f16*   scor = (f16*)(base + 18923520);        // 67,108,864 B -> ends 86,032,384
    int*   bestk = (int*)d_ws;                    // 32 KB

    prep<<<(NQ + NK) / 4, 256, 0, stream>>>(x_querry, e_k, Xh, Eh, marg, invn);
    gemm97<<<dim3(NQ / 128, NK / 128), 256, 0, stream>>>(Xh, Eh, invn, scor);
    scan_rescore<<<NQ, 256, 0, stream>>>(scor, marg, invn, x_querry, e_k, bestk);
    gather_out<<<NQ, 256, 0, stream>>>(bestk, e_p, x_block, (float*)d_out);
}

// Round 5
// 238.969 us; speedup vs baseline: 3.6747x; 1.0007x over previous
//
#include <hip/hip_runtime.h>
#include <math.h>

#define NQ   8192
#define NK   4096
#define DIM  768
#define LL   8

typedef _Float16 f16;
typedef __attribute__((ext_vector_type(8))) _Float16 f16x8;
typedef __attribute__((ext_vector_type(4))) float f32x4;
typedef unsigned long long u64;

__device__ inline unsigned ordf(float f) {           // monotonic f32->u32
    unsigned u = __float_as_uint(f);
    return (u & 0x80000000u) ? ~u : (u | 0x80000000u);
}

__device__ __forceinline__ void gload16(const void* g, void* l) {
    __builtin_amdgcn_global_load_lds((const __attribute__((address_space(1))) void*)g,
                                     (__attribute__((address_space(3))) void*)l, 16, 0, 0);
}

// ---------- prep: f16 conversion of x (rows 0..8191) and e_k (rows 8192..12287) ----------
__global__ __launch_bounds__(256) void prep(const float* __restrict__ xq,
                                            const float* __restrict__ ek,
                                            f16* __restrict__ Xh,
                                            f16* __restrict__ Eh,
                                            float* __restrict__ margin,
                                            float* __restrict__ inv_n) {
    const int wid = threadIdx.x >> 6, lane = threadIdx.x & 63;
    const int row = blockIdx.x * 4 + wid;              // 0..12287
    const bool isX = row < NQ;
    const float* src = isX ? xq + (size_t)row * DIM : ek + (size_t)(row - NQ) * DIM;
    f16* dst = isX ? Xh + (size_t)row * DIM : Eh + (size_t)(row - NQ) * DIM;
    float s2 = 0.f;
#pragma unroll
    for (int j = 0; j < DIM / 64; ++j) {
        const int c = j * 64 + lane;
        const float v = src[c];
        s2 = fmaf(v, v, s2);
        dst[c] = (f16)v;                               // RNE
    }
#pragma unroll
    for (int off = 32; off; off >>= 1) s2 += __shfl_xor(s2, off);
    if (lane == 0) {
        if (isX) margin[row] = sqrtf(s2) * 1.5e-4f + 2e-3f;   // ~13 sigma of fp16 noise
        else     inv_n[row - NQ] = 1.0f / fmaxf(sqrtf(s2), 1e-12f);
    }
}

// ---------- m97-structure fp16 MFMA GEMM: scor[b][k] = (xh.eh) * inv_n[k] ----------
// 128x128 tile, BK=64, 4 waves (2x2 of 64x64), global_load_lds w=16, linear LDS
__global__ __launch_bounds__(256) void gemm97(const f16* __restrict__ Xh,
                                              const f16* __restrict__ Eh,
                                              const float* __restrict__ inv_n,
                                              f16* __restrict__ scor) {
    __shared__ f16 A[128 * 64], B[128 * 64];
    const int t = threadIdx.x, lane = t & 63, wid = t >> 6;
    const int wm = wid & 1, wn = wid >> 1;
    const int qbase = blockIdx.x * 128, kbase = blockIdx.y * 128;

    f32x4 acc[4][4];
#pragma unroll
    for (int mi = 0; mi < 4; ++mi)
#pragma unroll
        for (int ni = 0; ni < 4; ++ni) acc[mi][ni] = (f32x4){0.f, 0.f, 0.f, 0.f};

    const int srow = wid * 8 + (lane >> 3);
    const int scol = (lane & 7) * 8;
    const f16* gA = Xh + (size_t)(qbase + srow) * DIM + scol;
    const f16* gB = Eh + (size_t)(kbase + srow) * DIM + scol;
    f16* lA = &A[wid * 512 + lane * 8];
    f16* lB = &B[wid * 512 + lane * 8];

    for (int kk = 0; kk < DIM; kk += 64) {
        __syncthreads();
#pragma unroll
        for (int p = 0; p < 4; ++p) {
            gload16(gA + (size_t)(p * 32) * DIM + kk, lA + p * 2048);
            gload16(gB + (size_t)(p * 32) * DIM + kk, lB + p * 2048);
        }
        __syncthreads();

#pragma unroll
        for (int kk2 = 0; kk2 < 2; ++kk2) {
            const int ko = kk2 * 32 + (lane >> 4) * 8;
            f16x8 ah[4], bh[4];
#pragma unroll
            for (int mi = 0; mi < 4; ++mi)
                ah[mi] = *(const f16x8*)&A[(wm * 64 + mi * 16 + (lane & 15)) * 64 + ko];
#pragma unroll
            for (int ni = 0; ni < 4; ++ni)
                bh[ni] = *(const f16x8*)&B[(wn * 64 + ni * 16 + (lane & 15)) * 64 + ko];
#pragma unroll
            for (int mi = 0; mi < 4; ++mi)
#pragma unroll
                for (int ni = 0; ni < 4; ++ni)
                    acc[mi][ni] = __builtin_amdgcn_mfma_f32_16x16x32_f16(ah[mi], bh[ni], acc[mi][ni], 0, 0, 0);
        }
    }

    const int rg = lane >> 4, cid = lane & 15;
    float invv[4];
    int key[4];
#pragma unroll
    for (int ni = 0; ni < 4; ++ni) {
        key[ni] = kbase + wn * 64 + ni * 16 + cid;
        invv[ni] = inv_n[key[ni]];
    }
#pragma unroll
    for (int mi = 0; mi < 4; ++mi)
#pragma unroll
        for (int rj = 0; rj < 4; ++rj) {
            const int row = qbase + wm * 64 + mi * 16 + rg * 4 + rj;
#pragma unroll
            for (int ni = 0; ni < 4; ++ni)
                scor[(size_t)row * NK + key[ni]] = (f16)(acc[mi][ni][rj] * invv[ni]);
        }
}

// ---------- scan: row max over f16 scores, margin test, exact f32 rescore, argmax ----------
__global__ __launch_bounds__(256) void scan_rescore(const f16* __restrict__ scor,
                                                    const float* __restrict__ margin,
                                                    const float* __restrict__ inv_n,
                                                    const float* __restrict__ xq,
                                                    const float* __restrict__ ek,
                                                    int* __restrict__ bestk) {
    const int r = blockIdx.x, t = threadIdx.x, lane = t & 63, wid = t >> 6;
    __shared__ float wmaxs[4];
    __shared__ u64 wbest[4];
    const f16* srow = scor + (size_t)r * NK + t * 16;
    const f16x8 s0 = *(const f16x8*)srow;
    const f16x8 s1 = *(const f16x8*)(srow + 8);
    float sc[16];
    float m = -INFINITY;
#pragma unroll
    for (int j = 0; j < 8; ++j) { sc[j] = (float)s0[j]; sc[j + 8] = (float)s1[j]; }
#pragma unroll
    for (int j = 0; j < 16; ++j) m = fmaxf(m, sc[j]);
#pragma unroll
    for (int off = 32; off; off >>= 1) m = fmaxf(m, __shfl_xor(m, off));
    if (lane == 0) wmaxs[wid] = m;
    __syncthreads();
    m = fmaxf(fmaxf(wmaxs[0], wmaxs[1]), fmaxf(wmaxs[2], wmaxs[3]));
    const float thr = m - margin[r];

    u64 bp = 0;
    const float4* xr = (const float4*)(xq + (size_t)r * DIM);
#pragma unroll 1
    for (int j = 0; j < 16; ++j) {
        if (sc[j] >= thr) {
            const int k = t * 16 + j;
            const float4* er = (const float4*)(ek + (size_t)k * DIM);
            float a0 = 0.f, a1 = 0.f, a2 = 0.f, a3 = 0.f;
#pragma unroll 8
            for (int p = 0; p < DIM / 4; ++p) {
                const float4 a = xr[p], b = er[p];
                a0 = fmaf(a.x, b.x, a0);
                a1 = fmaf(a.y, b.y, a1);
                a2 = fmaf(a.z, b.z, a2);
                a3 = fmaf(a.w, b.w, a3);
            }
            const float v = ((a0 + a1) + (a2 + a3)) * inv_n[k];
            const u64 p64 = ((u64)ordf(v) << 32) | (unsigned)(NK - 1 - k);
            bp = bp > p64 ? bp : p64;
        }
    }
#pragma unroll
    for (int off = 32; off; off >>= 1) {
        const u64 o = __shfl_xor(bp, off);
        bp = bp > o ? bp : o;
    }
    if (lane == 0) wbest[wid] = bp;
    __syncthreads();
    if (t == 0) {
        u64 b0 = wbest[0];
        b0 = b0 > wbest[1] ? b0 : wbest[1];
        b0 = b0 > wbest[2] ? b0 : wbest[2];
        b0 = b0 > wbest[3] ? b0 : wbest[3];
        bestk[r] = NK - 1 - (int)(unsigned)(b0 & 0xffffffffu);
    }
}

// ---------- flat grid-stride gather: one thread per output float4 ----------
// out layout (float4 units): Ek [0, 6291456) | Ev [6291456, 12582912) | xb [12582912, 14155776)
__global__ __launch_bounds__(256) void gather_flat(const int* __restrict__ bestk,
                                                   const float* __restrict__ e_p,
                                                   const float* __restrict__ x_block,
                                                   float4* __restrict__ o) {
    const int EK4 = NQ * 4 * (DIM / 4);          // 6,291,456
    const int XB4 = 2 * EK4;                     // 12,582,912
    const int TOT = XB4 + NQ * (DIM / 4);        // 14,155,776
    const int stride = gridDim.x * 256;
    const float4* ep4 = (const float4*)e_p;
    const float4* xb4 = (const float4*)x_block;
#pragma unroll 1
    for (int f = blockIdx.x * 256 + threadIdx.x; f < TOT; f += stride) {
        float4 v;
        if (f < XB4) {
            const int g = (f >= EK4) ? f - EK4 : f;      // position within half
            const int b = g / (4 * DIM / 4);             // /768: query row
            const int k = bestk[b];                       // wave-uniform (768 f4 per b)
            const int off = (f >= EK4) ? 4 * (DIM / 4) : 0;
            v = ep4[(size_t)k * (LL * DIM / 4) + off + (g - b * 768)];
        } else {
            v = xb4[f - XB4];
        }
        o[f] = v;
    }
}

// ---------- launch ----------
extern "C" void kernel_launch(void* const* d_in, const int* in_sizes, int n_in,
                              void* d_out, int out_size, void* d_ws, size_t ws_size,
                              hipStream_t stream) {
    const float* x_querry = (const float*)d_in[0];
    const float* x_block  = (const float*)d_in[1];
    const float* e_k      = (const float*)d_in[2];
    const float* e_p      = (const float*)d_in[3];

    // scratch carved from d_out (226.5 MB), fully consumed before gather overwrites it
    char* base = (char*)d_out;
    f16*   Xh   = (f16*)(base);                   // 12,582,912 B
    f16*   Eh   = (f16*)(base + 12582912);        //  6,291,456 B
    float* invn = (float*)(base + 18874368);      //     16,384 B
    float* marg = (float*)(base + 18890752);      //     32,768 B
    f16*   scor = (f16*)(base + 18923520);        // 67,108,864 B -> ends 86,032,384
    int*   bestk = (int*)d_ws;                    // 32 KB

    prep<<<(NQ + NK) / 4, 256, 0, stream>>>(x_querry, e_k, Xh, Eh, marg, invn);
    gemm97<<<dim3(NQ / 128, NK / 128), 256, 0, stream>>>(Xh, Eh, invn, scor);
    scan_rescore<<<NQ, 256, 0, stream>>>(scor, marg, invn, x_querry, e_k, bestk);
    gather_flat<<<2048, 256, 0, stream>>>(bestk, e_p, x_block, (float4*)d_out);
}

// Round 7
// 175.811 us; speedup vs baseline: 4.9948x; 1.3592x over previous
//
#include <hip/hip_runtime.h>
#include <math.h>

#define NQ   8192
#define NK   4096
#define DIM  768
#define LL   8

typedef _Float16 f16;
typedef __attribute__((ext_vector_type(4))) _Float16 f16x4;
typedef __attribute__((ext_vector_type(8))) _Float16 f16x8;
typedef __attribute__((ext_vector_type(4))) float f32x4;
typedef unsigned long long u64;

__device__ inline unsigned ordf(float f) {           // monotonic f32->u32
    unsigned u = __float_as_uint(f);
    return (u & 0x80000000u) ? ~u : (u | 0x80000000u);
}

__device__ __forceinline__ void gload16(const void* g, void* l) {
    __builtin_amdgcn_global_load_lds((const __attribute__((address_space(1))) void*)g,
                                     (__attribute__((address_space(3))) void*)l, 16, 0, 0);
}

// ---------- prep: f16 conversion of x (rows 0..8191) and e_k (rows 8192..12287) ----------
// vectorized: 3x f32x4 loads + 3x f16x4 stores per lane per row
__global__ __launch_bounds__(256) void prep(const float* __restrict__ xq,
                                            const float* __restrict__ ek,
                                            f16* __restrict__ Xh,
                                            f16* __restrict__ Eh,
                                            float* __restrict__ margin,
                                            float* __restrict__ inv_n) {
    const int wid = threadIdx.x >> 6, lane = threadIdx.x & 63;
    const int row = blockIdx.x * 4 + wid;              // 0..12287
    const bool isX = row < NQ;
    const f32x4* src = (const f32x4*)(isX ? xq + (size_t)row * DIM
                                          : ek + (size_t)(row - NQ) * DIM);
    f16x4* dst = (f16x4*)(isX ? Xh + (size_t)row * DIM : Eh + (size_t)(row - NQ) * DIM);
    float s2 = 0.f;
#pragma unroll
    for (int j = 0; j < 3; ++j) {
        const f32x4 v = src[j * 64 + lane];
        s2 = fmaf(v.x, v.x, fmaf(v.y, v.y, fmaf(v.z, v.z, fmaf(v.w, v.w, s2))));
        dst[j * 64 + lane] = (f16x4){(f16)v.x, (f16)v.y, (f16)v.z, (f16)v.w};
    }
#pragma unroll
    for (int off = 32; off; off >>= 1) s2 += __shfl_xor(s2, off);
    if (lane == 0) {
        if (isX) margin[row] = sqrtf(s2) * 1.5e-4f + 2e-3f;   // ~13 sigma of fp16 noise
        else     inv_n[row - NQ] = 1.0f / fmaxf(sqrtf(s2), 1e-12f);
    }
}

// ---------- m97-structure fp16 MFMA GEMM (UNCHANGED control) ----------
__global__ __launch_bounds__(256) void gemm97(const f16* __restrict__ Xh,
                                              const f16* __restrict__ Eh,
                                              const float* __restrict__ inv_n,
                                              f16* __restrict__ scor) {
    __shared__ f16 A[128 * 64], B[128 * 64];
    const int t = threadIdx.x, lane = t & 63, wid = t >> 6;
    const int wm = wid & 1, wn = wid >> 1;
    const int qbase = blockIdx.x * 128, kbase = blockIdx.y * 128;

    f32x4 acc[4][4];
#pragma unroll
    for (int mi = 0; mi < 4; ++mi)
#pragma unroll
        for (int ni = 0; ni < 4; ++ni) acc[mi][ni] = (f32x4){0.f, 0.f, 0.f, 0.f};

    const int srow = wid * 8 + (lane >> 3);
    const int scol = (lane & 7) * 8;
    const f16* gA = Xh + (size_t)(qbase + srow) * DIM + scol;
    const f16* gB = Eh + (size_t)(kbase + srow) * DIM + scol;
    f16* lA = &A[wid * 512 + lane * 8];
    f16* lB = &B[wid * 512 + lane * 8];

    for (int kk = 0; kk < DIM; kk += 64) {
        __syncthreads();
#pragma unroll
        for (int p = 0; p < 4; ++p) {
            gload16(gA + (size_t)(p * 32) * DIM + kk, lA + p * 2048);
            gload16(gB + (size_t)(p * 32) * DIM + kk, lB + p * 2048);
        }
        __syncthreads();

#pragma unroll
        for (int kk2 = 0; kk2 < 2; ++kk2) {
            const int ko = kk2 * 32 + (lane >> 4) * 8;
            f16x8 ah[4], bh[4];
#pragma unroll
            for (int mi = 0; mi < 4; ++mi)
                ah[mi] = *(const f16x8*)&A[(wm * 64 + mi * 16 + (lane & 15)) * 64 + ko];
#pragma unroll
            for (int ni = 0; ni < 4; ++ni)
                bh[ni] = *(const f16x8*)&B[(wn * 64 + ni * 16 + (lane & 15)) * 64 + ko];
#pragma unroll
            for (int mi = 0; mi < 4; ++mi)
#pragma unroll
                for (int ni = 0; ni < 4; ++ni)
                    acc[mi][ni] = __builtin_amdgcn_mfma_f32_16x16x32_f16(ah[mi], bh[ni], acc[mi][ni], 0, 0, 0);
        }
    }

    const int rg = lane >> 4, cid = lane & 15;
    float invv[4];
    int key[4];
#pragma unroll
    for (int ni = 0; ni < 4; ++ni) {
        key[ni] = kbase + wn * 64 + ni * 16 + cid;
        invv[ni] = inv_n[key[ni]];
    }
#pragma unroll
    for (int mi = 0; mi < 4; ++mi)
#pragma unroll
        for (int rj = 0; rj < 4; ++rj) {
            const int row = qbase + wm * 64 + mi * 16 + rg * 4 + rj;
#pragma unroll
            for (int ni = 0; ni < 4; ++ni)
                scor[(size_t)row * NK + key[ni]] = (f16)(acc[mi][ni][rj] * invv[ni]);
        }
}

// ---------- scan v2: row max, candidate list in LDS, wave-cooperative exact rescore ----------
__global__ __launch_bounds__(256) void scan_rescore(const f16* __restrict__ scor,
                                                    const float* __restrict__ margin,
                                                    const float* __restrict__ inv_n,
                                                    const float* __restrict__ xq,
                                                    const float* __restrict__ ek,
                                                    int* __restrict__ bestk) {
    const int r = blockIdx.x, t = threadIdx.x, lane = t & 63, wid = t >> 6;
    __shared__ float wmaxs[4];
    __shared__ u64 wbest[4];
    __shared__ int cnt;
    __shared__ int list[256];

    if (t == 0) cnt = 0;

    const f16* srow = scor + (size_t)r * NK + t * 16;
    const f16x8 s0 = *(const f16x8*)srow;
    const f16x8 s1 = *(const f16x8*)(srow + 8);
    float sc[16];
    float m = -INFINITY;
#pragma unroll
    for (int j = 0; j < 8; ++j) { sc[j] = (float)s0[j]; sc[j + 8] = (float)s1[j]; }
#pragma unroll
    for (int j = 0; j < 16; ++j) m = fmaxf(m, sc[j]);
#pragma unroll
    for (int off = 32; off; off >>= 1) m = fmaxf(m, __shfl_xor(m, off));
    if (lane == 0) wmaxs[wid] = m;
    __syncthreads();                               // covers wmaxs and cnt=0
    m = fmaxf(fmaxf(wmaxs[0], wmaxs[1]), fmaxf(wmaxs[2], wmaxs[3]));
    const float thr = m - margin[r];

    // collect candidates (argmax itself always qualifies -> cnt >= 1)
#pragma unroll
    for (int j = 0; j < 16; ++j) {
        if (sc[j] >= thr) {
            const int idx = atomicAdd(&cnt, 1);
            if (idx < 256) list[idx] = t * 16 + j;
        }
    }
    __syncthreads();
    const int n = cnt < 256 ? cnt : 256;

    // per-lane x fragment: 12 contiguous floats
    const f32x4* xr = (const f32x4*)(xq + (size_t)r * DIM);
    const f32x4 xa = xr[lane * 3], xb = xr[lane * 3 + 1], xc = xr[lane * 3 + 2];

    u64 best = 0;
    for (int e = wid; e < n; e += 4) {             // waves split the candidate list
        const int k = list[e];
        const f32x4* er = (const f32x4*)(ek + (size_t)k * DIM);
        const f32x4 ea = er[lane * 3], eb = er[lane * 3 + 1], ec = er[lane * 3 + 2];
        float s = xa.x * ea.x;
        s = fmaf(xa.y, ea.y, s); s = fmaf(xa.z, ea.z, s); s = fmaf(xa.w, ea.w, s);
        s = fmaf(xb.x, eb.x, s); s = fmaf(xb.y, eb.y, s); s = fmaf(xb.z, eb.z, s);
        s = fmaf(xb.w, eb.w, s); s = fmaf(xc.x, ec.x, s); s = fmaf(xc.y, ec.y, s);
        s = fmaf(xc.z, ec.z, s); s = fmaf(xc.w, ec.w, s);
#pragma unroll
        for (int off = 32; off; off >>= 1) s += __shfl_xor(s, off);
        const float v = s * inv_n[k];
        const u64 p64 = ((u64)ordf(v) << 32) | (unsigned)(NK - 1 - k);
        best = best > p64 ? best : p64;
    }
    if (lane == 0) wbest[wid] = best;              // s reduced -> uniform across lanes
    __syncthreads();
    if (t == 0) {
        u64 b0 = wbest[0];
        b0 = b0 > wbest[1] ? b0 : wbest[1];
        b0 = b0 > wbest[2] ? b0 : wbest[2];
        b0 = b0 > wbest[3] ? b0 : wbest[3];
        bestk[r] = NK - 1 - (int)(unsigned)(b0 & 0xffffffffu);
    }
}

// ---------- flat gather with nontemporal output stores ----------
__global__ __launch_bounds__(256) void gather_flat(const int* __restrict__ bestk,
                                                   const float* __restrict__ e_p,
                                                   const float* __restrict__ x_block,
                                                   f32x4* __restrict__ o) {
    const int EK4 = NQ * 4 * (DIM / 4);          // 6,291,456
    const int XB4 = 2 * EK4;                     // 12,582,912
    const int TOT = XB4 + NQ * (DIM / 4);        // 14,155,776
    const int stride = gridDim.x * 256;
    const f32x4* ep4 = (const f32x4*)e_p;
    const f32x4* xb4 = (const f32x4*)x_block;
#pragma unroll 1
    for (int f = blockIdx.x * 256 + threadIdx.x; f < TOT; f += stride) {
        f32x4 v;
        if (f < XB4) {
            const int g = (f >= EK4) ? f - EK4 : f;
            const int b = g / (4 * DIM / 4);
            const int k = bestk[b];
            const int off = (f >= EK4) ? 4 * (DIM / 4) : 0;
            v = ep4[(size_t)k * (LL * DIM / 4) + off + (g - b * 768)];
        } else {
            v = __builtin_nontemporal_load(&xb4[f - XB4]);
        }
        __builtin_nontemporal_store(v, &o[f]);
    }
}

// ---------- launch ----------
extern "C" void kernel_launch(void* const* d_in, const int* in_sizes, int n_in,
                              void* d_out, int out_size, void* d_ws, size_t ws_size,
                              hipStream_t stream) {
    const float* x_querry = (const float*)d_in[0];
    const float* x_block  = (const float*)d_in[1];
    const float* e_k      = (const float*)d_in[2];
    const float* e_p      = (const float*)d_in[3];

    // scratch carved from d_out (226.5 MB), fully consumed before gather overwrites it
    char* base = (char*)d_out;
    f16*   Xh   = (f16*)(base);                   // 12,582,912 B
    f16*   Eh   = (f16*)(base + 12582912);        //  6,291,456 B
    float* invn = (float*)(base + 18874368);      //     16,384 B
    float* marg = (float*)(base + 18890752);      //     32,768 B
    f16*   scor = (f16*)(base + 18923520);        // 67,108,864 B -> ends 86,032,384
    int*   bestk = (int*)d_ws;                    // 32 KB

    prep<<<(NQ + NK) / 4, 256, 0, stream>>>(x_querry, e_k, Xh, Eh, marg, invn);
    gemm97<<<dim3(NQ / 128, NK / 128), 256, 0, stream>>>(Xh, Eh, invn, scor);
    scan_rescore<<<NQ, 256, 0, stream>>>(scor, marg, invn, x_querry, e_k, bestk);
    gather_flat<<<2048, 256, 0, stream>>>(bestk, e_p, x_block, (f32x4*)d_out);
}